// Round 10
// baseline (227.594 us; speedup 1.0000x reference)
//
#include <hip/hip_runtime.h>
#include <math.h>

typedef unsigned short u16;
typedef unsigned int u32;
typedef __attribute__((ext_vector_type(8))) __bf16 bf16x8;
typedef __attribute__((ext_vector_type(4))) float f32x4;
typedef __attribute__((ext_vector_type(8))) unsigned short u16x8;

__device__ __forceinline__ u16 f2bf(float f) {
    u32 u = __builtin_bit_cast(u32, f);
    u32 r = (u + 0x7fffu + ((u >> 16) & 1u)) >> 16;
    return (u16)r;
}
__device__ __forceinline__ float bf2f(u16 h) {
    return __builtin_bit_cast(float, (u32)h << 16);
}
__device__ __forceinline__ float exp2v(float x) {
    float r;
    asm("v_exp_f32 %0, %1" : "=v"(r) : "v"(x));
    return r;
}
__device__ __forceinline__ u32 cvtpk(float lo, float hi) {
    u32 r;
    asm("v_cvt_pk_bf16_f32 %0, %1, %2" : "=v"(r) : "v"(lo), "v"(hi));
    return r;
}

#define GL16(gp, lp) __builtin_amdgcn_global_load_lds( \
    (const __attribute__((address_space(1))) u32*)(gp), \
    (__attribute__((address_space(3))) u32*)(lp), 16, 0, 0)

// RoPE a bf16x8 fragment: 4 (even,odd) pairs, cs4 = 4 (cos,sin) entries
__device__ __forceinline__ bf16x8 ropeQK(bf16x8 v, const float2* __restrict__ cs4) {
    union { bf16x8 b; u32 w[4]; } in, out;
    in.b = v;
#pragma unroll
    for (int i = 0; i < 4; ++i) {
        float2 cs = cs4[i];
        float e = bf2f((u16)(in.w[i] & 0xffff));
        float o = bf2f((u16)(in.w[i] >> 16));
        out.w[i] = cvtpk(e * cs.x - o * cs.y, fmaf(e, cs.y, o * cs.x));
    }
    return out.b;
}

// ---------------------------------------------------------------------------
// fp32 -> bf16 convert (vectorized, 8 elems/thread)
__global__ __launch_bounds__(256) void f2bker(const float* __restrict__ in, u16* __restrict__ out) {
    size_t i = ((size_t)blockIdx.x * 256 + threadIdx.x) * 8;
    float4 a = *(const float4*)(in + i);
    float4 b = *(const float4*)(in + i + 4);
    u16x8 w;
    w[0] = f2bf(a.x); w[1] = f2bf(a.y); w[2] = f2bf(a.z); w[3] = f2bf(a.w);
    w[4] = f2bf(b.x); w[5] = f2bf(b.y); w[6] = f2bf(b.z); w[7] = f2bf(b.w);
    *(u16x8*)(out + i) = w;
}

// ---------------------------------------------------------------------------
// transpose + convert: in fp32 [R][C] -> out bf16 [C][R]  (64x64 tiles)
__global__ __launch_bounds__(256) void wtrans(const float* __restrict__ in, u16* __restrict__ out,
                                              int R, int C) {
    __shared__ u16 t[64 * 65];
    const int tid = threadIdx.x;
    const int c0 = blockIdx.x * 64, r0 = blockIdx.y * 64;
#pragma unroll
    for (int it = 0; it < 4; ++it) {
        int f = it * 256 + tid;
        int row = f >> 4, c4 = (f & 15) * 4;
        float4 v = *(const float4*)(in + (size_t)(r0 + row) * C + c0 + c4);
        t[row * 65 + c4 + 0] = f2bf(v.x);
        t[row * 65 + c4 + 1] = f2bf(v.y);
        t[row * 65 + c4 + 2] = f2bf(v.z);
        t[row * 65 + c4 + 3] = f2bf(v.w);
    }
    __syncthreads();
#pragma unroll
    for (int it = 0; it < 2; ++it) {
        int f = it * 256 + tid;
        int oc = f >> 3, r8 = (f & 7) * 8;
        u16x8 w;
#pragma unroll
        for (int j = 0; j < 8; ++j) w[j] = t[(r8 + j) * 65 + oc];
        *(u16x8*)(out + (size_t)(c0 + oc) * R + r0 + r8) = w;
    }
}

// ---------------------------------------------------------------------------
// RoPE table: tab[t][d2] = (cos(t*invf), sin(t*invf)), T=2048, 32 pairs
__global__ __launch_bounds__(256) void rope_tab(float2* __restrict__ tab) {
    int i = blockIdx.x * 256 + threadIdx.x;   // 65536
    int tpos = i >> 5, d2 = i & 31;
    float invf = powf(10000.f, -(float)(2 * d2) / 64.f);
    float fr = (float)tpos * invf;
    tab[i] = make_float2(cosf(fr), sinf(fr));
}

// RoPE in-place on K only (B,H,T,D) bf16 (Q is roped inside attn)
__global__ __launch_bounds__(256) void rope_ip(u16* __restrict__ K,
                                               const float2* __restrict__ tab) {
    int i = blockIdx.x * 256 + threadIdx.x;   // 4,194,304 pairs
    u32* p = (u32*)K + i;
    int d2 = i & 31, tpos = (i >> 5) & 2047;
    float2 cs = tab[tpos * 32 + d2];
    u32 v = *p;
    float xe = bf2f((u16)(v & 0xffff));
    float xo = bf2f((u16)(v >> 16));
    float re = xe * cs.x - xo * cs.y;
    float ro = xe * cs.y + xo * cs.x;
    *p = (u32)f2bf(re) | ((u32)f2bf(ro) << 16);
}

// ---------------------------------------------------------------------------
// Depth-2 counted-vmcnt pipelined GEMM, BK=32, 128x128 tile, 256 threads =
// 4 waves (2x2, 64x64 each), double-buffered LDS 32 KiB -> 4 blocks/CU
// (launch_bounds(256,4), VGPR<=128). Prologue stages tiles 0,1. Per iter:
// vmcnt(4) waits ONLY tile t (t+1's 4 loads in flight) -> s_barrier ->
// ds_read+MFMA -> lgkmcnt(0)+s_barrier -> STAGE(t+2 -> buf t&1).
// Swizzle (64-B rows, 2 bits): write source col (tid&3)*16 ^ ((row&3)<<4),
// read g*16 ^ ((c&3)<<4) (fragment rows ≡ c mod 4). K = 1024 fixed.
// MODE 0: Cf[m][n] = acc + bias[n]. MODE 1: qkv scatter (V transposed).
template <int MODE>
__global__ __launch_bounds__(256, 4) void gemm2p(
    const u16* __restrict__ A, const u16* __restrict__ Bt,
    const float* __restrict__ bias, float* __restrict__ Cf,
    u16* __restrict__ Qb, u16* __restrict__ Kb, u16* __restrict__ VbT,
    int N, int nbx) {
    __shared__ __align__(16) u16 ls[2][2][128 * 32];   // [buf][A/B][row][col32]
    const int tid = threadIdx.x;
    const int w = tid >> 6, lane = tid & 63;
    const int c = lane & 15, g = lane >> 4;
    const int wr = w >> 1, wc = w & 1;

    // bijective XCD swizzle (gridDim.x % 8 == 0)
    const int nb8 = (int)gridDim.x >> 3;
    const int bid = (int)blockIdx.x;
    const int nid = (bid & 7) * nb8 + (bid >> 3);
    const int by = nid / nbx, bx = nid - by * nbx;
    const int m0 = by * 128, n0 = bx * 128;

    f32x4 acc[4][4] = {};

    // staging: thread covers physical LDS bytes tid*16 of each 4 KB pass
    // (row rl = tid>>2 [+64 pass1], phys col (tid&3)*16). Source col is
    // inverse-swizzled (2-bit involution) so swizzled ds_read is linear.
    const int rl = tid >> 2;                   // 0..63
    const unsigned cb = ((unsigned)(tid & 3) * 16) ^ (((unsigned)rl & 3) << 4);
    const u16* gA = A + (size_t)(m0 + rl) * 1024 + (cb >> 1);
    const u16* gB = Bt + (size_t)(n0 + rl) * 1024 + (cb >> 1);
    const unsigned wb = (unsigned)__builtin_amdgcn_readfirstlane(w * 1024);
    char* lsb = (char*)ls;

#define STAGE(t_, buf_) do {                                                  \
        const u16* _ga = gA + (t_) * 32;                                      \
        const u16* _gb = gB + (t_) * 32;                                      \
        char* _la = lsb + (buf_) * 16384 + wb;                                \
        char* _lb = _la + 8192;                                               \
        GL16(_ga, _la);                                                       \
        GL16(_ga + 64 * 1024, _la + 4096);                                    \
        GL16(_gb, _lb);                                                       \
        GL16(_gb + 64 * 1024, _lb + 4096);                                    \
    } while (0)

    const unsigned swz = ((unsigned)(c & 3)) << 4;

    STAGE(0, 0);
    STAGE(1, 1);

    for (int t = 0; t < 32; ++t) {
        const int buf = t & 1;
        __builtin_amdgcn_sched_barrier(0);
        if (t == 31) asm volatile("s_waitcnt vmcnt(0)" ::: "memory");
        else         asm volatile("s_waitcnt vmcnt(4)" ::: "memory");
        __builtin_amdgcn_sched_barrier(0);
        __builtin_amdgcn_s_barrier();           // buf[t&1] fully staged
        __builtin_amdgcn_sched_barrier(0);

        const char* la = lsb + buf * 16384;
        const char* lb2 = la + 8192;
        bf16x8 af[4], bfr[4];
#pragma unroll
        for (int i = 0; i < 4; ++i)
            af[i] = *(const bf16x8*)(la + (unsigned)((wr * 64 + i * 16 + c) * 64) + ((unsigned)(g * 16) ^ swz));
#pragma unroll
        for (int j = 0; j < 4; ++j)
            bfr[j] = *(const bf16x8*)(lb2 + (unsigned)((wc * 64 + j * 16 + c) * 64) + ((unsigned)(g * 16) ^ swz));
        __builtin_amdgcn_s_setprio(1);
#pragma unroll
        for (int i = 0; i < 4; ++i)
#pragma unroll
            for (int j = 0; j < 4; ++j)
                acc[i][j] = __builtin_amdgcn_mfma_f32_16x16x32_bf16(af[i], bfr[j], acc[i][j], 0, 0, 0);
        __builtin_amdgcn_s_setprio(0);
        __builtin_amdgcn_sched_barrier(0);
        asm volatile("s_waitcnt lgkmcnt(0)" ::: "memory");
        __builtin_amdgcn_s_barrier();           // all reads of buf done
        __builtin_amdgcn_sched_barrier(0);
        if (t < 30) STAGE(t + 2, buf);          // overwrite buf for t+2
    }
#undef STAGE

    if (MODE == 0) {
#pragma unroll
        for (int i = 0; i < 4; ++i)
#pragma unroll
            for (int r = 0; r < 4; ++r) {
                int m = m0 + wr * 64 + i * 16 + g * 4 + r;
#pragma unroll
                for (int j = 0; j < 4; ++j) {
                    int n = n0 + wc * 64 + j * 16 + c;
                    Cf[(size_t)m * N + n] = acc[i][j][r] + bias[n];
                }
            }
    } else {
        const int part = n0 >> 10;             // tile never crosses 1024-boundary
#pragma unroll
        for (int i = 0; i < 4; ++i)
#pragma unroll
            for (int r = 0; r < 4; ++r) {
                int m = m0 + wr * 64 + i * 16 + g * 4 + r;
                int b = m >> 11, tt = m & 2047;
#pragma unroll
                for (int j = 0; j < 4; ++j) {
                    int n = n0 + wc * 64 + j * 16 + c;
                    int e = n & 1023, hh = e >> 6, d = e & 63;
                    float v = acc[i][j][r] + bias[n];
                    u16 bv = f2bf(v);
                    if (part == 0)
                        Qb[(((size_t)b * 16 + hh) * 2048 + tt) * 64 + d] = bv;
                    else if (part == 1)
                        Kb[(((size_t)b * 16 + hh) * 2048 + tt) * 64 + d] = bv;
                    else
                        VbT[(((size_t)b * 16 + hh) * 64 + d) * 2048 + tt] = bv;
                }
            }
    }
}

// ---------------------------------------------------------------------------
// Flash attention, swapped-operand form; Q roped in-register at start.
// 1024 blocks, 256 threads (4 waves x 32 q each; block = 128 q rows).
__global__ __launch_bounds__(256, 3) void attn_fwd(
    const u16* __restrict__ Qb, const u16* __restrict__ Kb,
    const u16* __restrict__ VbT, u16* __restrict__ Ob,
    const float2* __restrict__ tab) {
    __shared__ __align__(16) u16 Kt[2][4096];   // [buf][kv=64][d=64] swizzled
    __shared__ __align__(16) u16 Vt[2][4096];   // [buf][d=64][kv=64] swizzled
    __shared__ __align__(16) u16 Pt[4][2048];   // per-wave [q=32][kv=64] swizzled
    const int tid = threadIdx.x, wv = tid >> 6, lane = tid & 63;
    const int g = lane >> 4, c = lane & 15;
    const int bid = blockIdx.x;                 // 0..1023
    const int xcd = bid & 7, slot = bid >> 3;
    const int bh = (xcd << 3) | (slot >> 4);
    const int blk = 15 - (slot & 15);
    const int b = bh >> 4, h = bh & 15;
    const int q0 = blk * 128;
    const int q0w = q0 + wv * 32;
    const int qlo = q0w + c, qhi = q0w + 16 + c;
    const float CSC = 0.18033688011112042f;     // 0.125 * log2(e)

    const u16* qp = Qb + ((size_t)bh * 2048 + qlo) * 64 + g * 8;
    const float2* tql = tab + qlo * 32 + g * 4;
    const float2* tqh = tab + qhi * 32 + g * 4;
    bf16x8 bq0l = ropeQK(*(const bf16x8*)(qp), tql);
    bf16x8 bq1l = ropeQK(*(const bf16x8*)(qp + 32), tql + 16);
    bf16x8 bq0h = ropeQK(*(const bf16x8*)(qp + 16 * 64), tqh);
    bf16x8 bq1h = ropeQK(*(const bf16x8*)(qp + 16 * 64 + 32), tqh + 16);

    float m_lo = -INFINITY, l_lo = 0.f;
    float m_hi = -INFINITY, l_hi = 0.f;
    f32x4 accL[4] = {}, accH[4] = {};

    const int stRow = tid >> 3;                 // 0..31
    const int stCol = (tid & 7) * 8;            // 0..56
    const u16* gK = Kb + (size_t)bh * 2048 * 64 + (size_t)stRow * 64 + stCol;
    const u16* gV = VbT + (size_t)bh * 64 * 2048 + (size_t)stRow * 2048 + stCol;
    const unsigned sw8 = (unsigned)(stRow & 7) << 4;
    const unsigned sAd0 = ((unsigned)(stRow * 128 + stCol * 2)) ^ sw8;
    const unsigned sAd1 = ((unsigned)((stRow + 32) * 128 + stCol * 2)) ^ sw8;
    const unsigned swz = (unsigned)(c & 7) << 4;
    char* pw = (char*)&Pt[wv][0];

    const int ktend = 2 * blk + 1;
    const int ktmax_w = (q0w + 31) >> 6;

    u16x8 kr0 = *(const u16x8*)(gK);
    u16x8 kr1 = *(const u16x8*)(gK + 32 * 64);
    u16x8 vr0 = *(const u16x8*)(gV);
    u16x8 vr1 = *(const u16x8*)(gV + 32 * 2048);
    *(u16x8*)((char*)Kt[0] + sAd0) = kr0;
    *(u16x8*)((char*)Kt[0] + sAd1) = kr1;
    *(u16x8*)((char*)Vt[0] + sAd0) = vr0;
    *(u16x8*)((char*)Vt[0] + sAd1) = vr1;
    int cur = 0;

    for (int kt = 0; kt <= ktend; ++kt) {
        __syncthreads();
        if (kt < ktend) {
            const u16* nK = gK + (size_t)(kt + 1) * 64 * 64;
            const u16* nV = gV + (size_t)(kt + 1) * 64;
            kr0 = *(const u16x8*)(nK);
            kr1 = *(const u16x8*)(nK + 32 * 64);
            vr0 = *(const u16x8*)(nV);
            vr1 = *(const u16x8*)(nV + 32 * 2048);
        }
        if (kt <= ktmax_w) {
            const char* Kc = (const char*)Kt[cur];
            const char* Vc = (const char*)Vt[cur];

            f32x4 sl[4] = {}, sh[4] = {};
#pragma unroll
            for (int j = 0; j < 4; ++j) {
                unsigned rb = (unsigned)((16 * j + c) * 128 + g * 16);
                bf16x8 ka0 = *(const bf16x8*)(Kc + (rb ^ swz));
                bf16x8 ka1 = *(const bf16x8*)(Kc + ((rb + 64) ^ swz));
                sl[j] = __builtin_amdgcn_mfma_f32_16x16x32_bf16(ka0, bq0l, sl[j], 0, 0, 0);
                sl[j] = __builtin_amdgcn_mfma_f32_16x16x32_bf16(ka1, bq1l, sl[j], 0, 0, 0);
                sh[j] = __builtin_amdgcn_mfma_f32_16x16x32_bf16(ka0, bq0h, sh[j], 0, 0, 0);
                sh[j] = __builtin_amdgcn_mfma_f32_16x16x32_bf16(ka1, bq1h, sh[j], 0, 0, 0);
            }

            const int kvb = kt * 64 + 4 * g;
            if (kt * 64 + 63 > q0w) {
#pragma unroll
                for (int j = 0; j < 4; ++j)
#pragma unroll
                    for (int r = 0; r < 4; ++r)
                        if (kvb + 16 * j + r > qlo) sl[j][r] = -INFINITY;
            }
            if (kt * 64 + 63 > q0w + 16) {
#pragma unroll
                for (int j = 0; j < 4; ++j)
#pragma unroll
                    for (int r = 0; r < 4; ++r)
                        if (kvb + 16 * j + r > qhi) sh[j][r] = -INFINITY;
            }

#pragma unroll
            for (int half = 0; half < 2; ++half) {
                f32x4* s = half ? sh : sl;
                float& m_r = half ? m_hi : m_lo;
                float& l_r = half ? l_hi : l_lo;
                f32x4* acc = half ? accH : accL;
                float mx = -INFINITY;
#pragma unroll
                for (int j = 0; j < 4; ++j)
#pragma unroll
                    for (int r = 0; r < 4; ++r) mx = fmaxf(mx, s[j][r]);
                mx = fmaxf(mx, __shfl_xor(mx, 16));
                mx = fmaxf(mx, __shfl_xor(mx, 32));
                if (!__all((mx - m_r) * CSC <= 8.f)) {
                    float mn = fmaxf(m_r, mx);
                    float al = exp2v((m_r - mn) * CSC);
                    l_r *= al;
#pragma unroll
                    for (int dj = 0; dj < 4; ++dj) acc[dj] *= al;
                    m_r = mn;
                }
                const float mc = m_r * CSC;
                float sum = 0.f;
                u32 pp[8];
#pragma unroll
                for (int j = 0; j < 4; ++j) {
#pragma unroll
                    for (int t2 = 0; t2 < 2; ++t2) {
                        float p0 = exp2v(fmaf(s[j][2 * t2], CSC, -mc));
                        float p1 = exp2v(fmaf(s[j][2 * t2 + 1], CSC, -mc));
                        sum += p0 + p1;
                        pp[j * 2 + t2] = cvtpk(p0, p1);
                    }
                }
                sum += __shfl_xor(sum, 16);
                sum += __shfl_xor(sum, 32);
                l_r += sum;
                unsigned rq = (unsigned)(c + 16 * half) * 128;
#pragma unroll
                for (int j = 0; j < 4; ++j) {
                    uint2 w2;
                    w2.x = pp[j * 2];
                    w2.y = pp[j * 2 + 1];
                    *(uint2*)(pw + ((rq + j * 32 + g * 8) ^ swz)) = w2;
                }
            }

#pragma unroll
            for (int ks = 0; ks < 2; ++ks) {
                bf16x8 pbl = *(const bf16x8*)(pw + ((unsigned)(c * 128 + ks * 64 + g * 16) ^ swz));
                bf16x8 pbh = *(const bf16x8*)(pw + ((unsigned)((c + 16) * 128 + ks * 64 + g * 16) ^ swz));
#pragma unroll
                for (int dj = 0; dj < 4; ++dj) {
                    unsigned vb = (unsigned)((dj * 16 + c) * 128 + ks * 64 + g * 16) ^ swz;
                    bf16x8 va = *(const bf16x8*)(Vc + vb);
                    accL[dj] = __builtin_amdgcn_mfma_f32_16x16x32_bf16(va, pbl, accL[dj], 0, 0, 0);
                    accH[dj] = __builtin_amdgcn_mfma_f32_16x16x32_bf16(va, pbh, accH[dj], 0, 0, 0);
                }
            }
        }

        if (kt < ktend) {
            int nb = cur ^ 1;
            *(u16x8*)((char*)Kt[nb] + sAd0) = kr0;
            *(u16x8*)((char*)Kt[nb] + sAd1) = kr1;
            *(u16x8*)((char*)Vt[nb] + sAd0) = vr0;
            *(u16x8*)((char*)Vt[nb] + sAd1) = vr1;
            cur = nb;
        }
    }

#pragma unroll
    for (int half = 0; half < 2; ++half) {
        const f32x4* acc = half ? accH : accL;
        float inv = 1.f / (half ? l_hi : l_lo);
        int q = half ? qhi : qlo;
        u16* ob = Ob + ((size_t)b * 2048 + q) * 1024 + h * 64;
#pragma unroll
        for (int dj = 0; dj < 4; ++dj) {
            f32x4 o = acc[dj] * inv;
            uint2 w;
            w.x = cvtpk(o[0], o[1]);
            w.y = cvtpk(o[2], o[3]);
            *(uint2*)(ob + dj * 16 + 4 * g) = w;
        }
    }
}

// ---------------------------------------------------------------------------
extern "C" void kernel_launch(void* const* d_in, const int* in_sizes, int n_in,
                              void* d_out, int out_size, void* d_ws, size_t ws_size,
                              hipStream_t stream) {
    const float* x = (const float*)d_in[0];
    const float* Wqkv = (const float*)d_in[1];
    const float* bqkv = (const float*)d_in[2];
    const float* Wproj = (const float*)d_in[3];
    const float* bproj = (const float*)d_in[4];
    float* out = (float*)d_out;

    char* ws = (char*)d_ws;
    u16* xb = (u16*)(ws);                       // 16,777,216 B; reused as Ob
    u16* WqkvT = (u16*)(ws + 16777216);         //  6,291,456 B
    u16* WprojT = (u16*)(ws + 23068672);        //  2,097,152 B
    u16* Qb = (u16*)(ws + 25165824);            // 16,777,216 B
    u16* Kb = (u16*)(ws + 41943040);            // 16,777,216 B
    u16* VbT = (u16*)(ws + 58720256);           // 16,777,216 B
    float2* tab = (float2*)(ws + 75497472);     //    524,288 B  (total ~76 MB)

    f2bker<<<4096, 256, 0, stream>>>(x, xb);
    wtrans<<<dim3(48, 16), 256, 0, stream>>>(Wqkv, WqkvT, 1024, 3072);
    wtrans<<<dim3(16, 16), 256, 0, stream>>>(Wproj, WprojT, 1024, 1024);
    rope_tab<<<256, 256, 0, stream>>>(tab);
    gemm2p<1><<<1536, 256, 0, stream>>>(xb, WqkvT, bqkv, nullptr, Qb, Kb, VbT,
                                        3072, 24);
    rope_ip<<<16384, 256, 0, stream>>>(Kb, tab);
    attn_fwd<<<1024, 256, 0, stream>>>(Qb, Kb, VbT, xb /*Ob*/, tab);
    gemm2p<0><<<512, 256, 0, stream>>>(xb, WprojT, bproj, out,
                                       nullptr, nullptr, nullptr, 1024, 8);
}

// Round 11
// 205.895 us; speedup vs baseline: 1.1054x; 1.1054x over previous
//
#include <hip/hip_runtime.h>
#include <math.h>

typedef unsigned short u16;
typedef unsigned int u32;
typedef __attribute__((ext_vector_type(8))) __bf16 bf16x8;
typedef __attribute__((ext_vector_type(4))) float f32x4;
typedef __attribute__((ext_vector_type(8))) unsigned short u16x8;

__device__ __forceinline__ u16 f2bf(float f) {
    u32 u = __builtin_bit_cast(u32, f);
    u32 r = (u + 0x7fffu + ((u >> 16) & 1u)) >> 16;
    return (u16)r;
}
__device__ __forceinline__ float bf2f(u16 h) {
    return __builtin_bit_cast(float, (u32)h << 16);
}
__device__ __forceinline__ float exp2v(float x) {
    float r;
    asm("v_exp_f32 %0, %1" : "=v"(r) : "v"(x));
    return r;
}
__device__ __forceinline__ u32 cvtpk(float lo, float hi) {
    u32 r;
    asm("v_cvt_pk_bf16_f32 %0, %1, %2" : "=v"(r) : "v"(lo), "v"(hi));
    return r;
}

#define GL16(gp, lp) __builtin_amdgcn_global_load_lds( \
    (const __attribute__((address_space(1))) u32*)(gp), \
    (__attribute__((address_space(3))) u32*)(lp), 16, 0, 0)

// RoPE a bf16x8 fragment: 4 (even,odd) pairs, cs4 = 4 (cos,sin) entries
__device__ __forceinline__ bf16x8 ropeQK(bf16x8 v, const float2* __restrict__ cs4) {
    union { bf16x8 b; u32 w[4]; } in, out;
    in.b = v;
#pragma unroll
    for (int i = 0; i < 4; ++i) {
        float2 cs = cs4[i];
        float e = bf2f((u16)(in.w[i] & 0xffff));
        float o = bf2f((u16)(in.w[i] >> 16));
        out.w[i] = cvtpk(e * cs.x - o * cs.y, fmaf(e, cs.y, o * cs.x));
    }
    return out.b;
}

// ---------------------------------------------------------------------------
// fp32 -> bf16 convert (vectorized, 8 elems/thread)
__global__ __launch_bounds__(256) void f2bker(const float* __restrict__ in, u16* __restrict__ out) {
    size_t i = ((size_t)blockIdx.x * 256 + threadIdx.x) * 8;
    float4 a = *(const float4*)(in + i);
    float4 b = *(const float4*)(in + i + 4);
    u16x8 w;
    w[0] = f2bf(a.x); w[1] = f2bf(a.y); w[2] = f2bf(a.z); w[3] = f2bf(a.w);
    w[4] = f2bf(b.x); w[5] = f2bf(b.y); w[6] = f2bf(b.z); w[7] = f2bf(b.w);
    *(u16x8*)(out + i) = w;
}

// ---------------------------------------------------------------------------
// transpose + convert: in fp32 [R][C] -> out bf16 [C][R]  (64x64 tiles)
__global__ __launch_bounds__(256) void wtrans(const float* __restrict__ in, u16* __restrict__ out,
                                              int R, int C) {
    __shared__ u16 t[64 * 65];
    const int tid = threadIdx.x;
    const int c0 = blockIdx.x * 64, r0 = blockIdx.y * 64;
#pragma unroll
    for (int it = 0; it < 4; ++it) {
        int f = it * 256 + tid;
        int row = f >> 4, c4 = (f & 15) * 4;
        float4 v = *(const float4*)(in + (size_t)(r0 + row) * C + c0 + c4);
        t[row * 65 + c4 + 0] = f2bf(v.x);
        t[row * 65 + c4 + 1] = f2bf(v.y);
        t[row * 65 + c4 + 2] = f2bf(v.z);
        t[row * 65 + c4 + 3] = f2bf(v.w);
    }
    __syncthreads();
#pragma unroll
    for (int it = 0; it < 2; ++it) {
        int f = it * 256 + tid;
        int oc = f >> 3, r8 = (f & 7) * 8;
        u16x8 w;
#pragma unroll
        for (int j = 0; j < 8; ++j) w[j] = t[(r8 + j) * 65 + oc];
        *(u16x8*)(out + (size_t)(c0 + oc) * R + r0 + r8) = w;
    }
}

// ---------------------------------------------------------------------------
// RoPE table: tab[t][d2] = (cos(t*invf), sin(t*invf)), T=2048, 32 pairs
__global__ __launch_bounds__(256) void rope_tab(float2* __restrict__ tab) {
    int i = blockIdx.x * 256 + threadIdx.x;   // 65536
    int tpos = i >> 5, d2 = i & 31;
    float invf = powf(10000.f, -(float)(2 * d2) / 64.f);
    float fr = (float)tpos * invf;
    tab[i] = make_float2(cosf(fr), sinf(fr));
}

// RoPE in-place on K only (B,H,T,D) bf16 (Q is roped inside attn)
__global__ __launch_bounds__(256) void rope_ip(u16* __restrict__ K,
                                               const float2* __restrict__ tab) {
    int i = blockIdx.x * 256 + threadIdx.x;   // 4,194,304 pairs
    u32* p = (u32*)K + i;
    int d2 = i & 31, tpos = (i >> 5) & 2047;
    float2 cs = tab[tpos * 32 + d2];
    u32 v = *p;
    float xe = bf2f((u16)(v & 0xffff));
    float xo = bf2f((u16)(v >> 16));
    float re = xe * cs.x - xo * cs.y;
    float ro = xe * cs.y + xo * cs.x;
    *p = (u32)f2bf(re) | ((u32)f2bf(ro) << 16);
}

// ---------------------------------------------------------------------------
// Depth-2 counted-vmcnt pipelined GEMM (r9 body, best measured): BK=64,
// 128x128 tile, 256 threads = 4 waves (2x2, 64x64 each), double-buffered
// 64 KiB LDS -> 2 blocks/CU. NEW (r11): 2D-clustered-per-XCD block mapping —
// each XCD owns an 8-row stripe of by; within it blocks walk 4x4 (by,bx)
// clusters so the active A-slice (1 MB) + B-slice (1 MB) are L2-resident.
// Requires nby == 64 and gridDim.x == 512*nbx/8... generally:
//   xcd = bid&7, s = bid>>3, ncc = nbx/4,
//   by = xcd*8 + (cidx/ncc)*4 + (w>>2), bx = (cidx%ncc)*4 + (w&3),
//   cidx = s>>4, w = s&15.
// MODE 0: Cf[m][n] = acc + bias[n]. MODE 1: qkv scatter (V transposed).
template <int MODE>
__global__ __launch_bounds__(256, 2) void gemm2p(
    const u16* __restrict__ A, const u16* __restrict__ Bt,
    const float* __restrict__ bias, float* __restrict__ Cf,
    u16* __restrict__ Qb, u16* __restrict__ Kb, u16* __restrict__ VbT,
    int N, int nbx) {
    __shared__ __align__(16) u16 ls[2][2][128 * 64];   // [buf][A/B][row][col]
    const int tid = threadIdx.x;
    const int w = tid >> 6, lane = tid & 63;
    const int c = lane & 15, g = lane >> 4;
    const int wr = w >> 1, wc = w & 1;

    // 2D-clustered XCD mapping (bijective; nbx % 4 == 0, grid = 8*8*nbx... )
    const int bid = (int)blockIdx.x;
    const int xcd = bid & 7, s = bid >> 3;
    const int ncc = nbx >> 2;                  // cluster columns
    const int cidx = s >> 4, w2 = s & 15;      // cluster index / within-cluster
    const int by = xcd * 8 + (cidx / ncc) * 4 + (w2 >> 2);
    const int bx = (cidx % ncc) * 4 + (w2 & 3);
    const int m0 = by * 128, n0 = bx * 128;

    f32x4 acc[4][4] = {};

    const int rl = tid >> 3;                   // 0..31
    const unsigned cb = ((unsigned)(tid & 7) * 16) ^ (((unsigned)rl & 7) << 4);
    const u16* gA = A + (size_t)(m0 + rl) * 1024 + (cb >> 1);
    const u16* gB = Bt + (size_t)(n0 + rl) * 1024 + (cb >> 1);
    const unsigned wb = (unsigned)__builtin_amdgcn_readfirstlane(w * 1024);
    char* lsb = (char*)ls;

#define STAGE(t_, buf_) do {                                                  \
        const u16* _ga = gA + (t_) * 64;                                      \
        const u16* _gb = gB + (t_) * 64;                                      \
        char* _la = lsb + (buf_) * 32768 + wb;                                \
        char* _lb = _la + 16384;                                              \
        GL16(_ga, _la);                                                       \
        GL16(_ga + 32 * 1024, _la + 4096);                                    \
        GL16(_ga + 64 * 1024, _la + 8192);                                    \
        GL16(_ga + 96 * 1024, _la + 12288);                                   \
        GL16(_gb, _lb);                                                       \
        GL16(_gb + 32 * 1024, _lb + 4096);                                    \
        GL16(_gb + 64 * 1024, _lb + 8192);                                    \
        GL16(_gb + 96 * 1024, _lb + 12288);                                   \
    } while (0)

    const unsigned swz = ((unsigned)(c & 7)) << 4;

    STAGE(0, 0);
    STAGE(1, 1);

    for (int t = 0; t < 16; ++t) {
        const int buf = t & 1;
        __builtin_amdgcn_sched_barrier(0);
        if (t == 15) asm volatile("s_waitcnt vmcnt(0)" ::: "memory");
        else         asm volatile("s_waitcnt vmcnt(8)" ::: "memory");
        __builtin_amdgcn_sched_barrier(0);
        __builtin_amdgcn_s_barrier();           // buf[t&1] fully staged
        __builtin_amdgcn_sched_barrier(0);

        const char* la = lsb + buf * 32768;
        const char* lb2 = la + 16384;
        bf16x8 af[4][2], bfr[4][2];
#pragma unroll
        for (int i = 0; i < 4; ++i) {
            unsigned rb = (unsigned)((wr * 64 + i * 16 + c) * 128);
            af[i][0] = *(const bf16x8*)(la + ((rb + g * 16) ^ swz));
            af[i][1] = *(const bf16x8*)(la + ((rb + 64 + g * 16) ^ swz));
        }
#pragma unroll
        for (int j = 0; j < 4; ++j) {
            unsigned rb = (unsigned)((wc * 64 + j * 16 + c) * 128);
            bfr[j][0] = *(const bf16x8*)(lb2 + ((rb + g * 16) ^ swz));
            bfr[j][1] = *(const bf16x8*)(lb2 + ((rb + 64 + g * 16) ^ swz));
        }
        __builtin_amdgcn_s_setprio(1);
#pragma unroll
        for (int i = 0; i < 4; ++i)
#pragma unroll
            for (int j = 0; j < 4; ++j) {
                acc[i][j] = __builtin_amdgcn_mfma_f32_16x16x32_bf16(af[i][0], bfr[j][0], acc[i][j], 0, 0, 0);
                acc[i][j] = __builtin_amdgcn_mfma_f32_16x16x32_bf16(af[i][1], bfr[j][1], acc[i][j], 0, 0, 0);
            }
        __builtin_amdgcn_s_setprio(0);
        __builtin_amdgcn_sched_barrier(0);
        asm volatile("s_waitcnt lgkmcnt(0)" ::: "memory");
        __builtin_amdgcn_s_barrier();           // all reads of buf done
        __builtin_amdgcn_sched_barrier(0);
        if (t < 14) STAGE(t + 2, buf);          // overwrite buf for t+2
    }
#undef STAGE

    if (MODE == 0) {
#pragma unroll
        for (int i = 0; i < 4; ++i)
#pragma unroll
            for (int r = 0; r < 4; ++r) {
                int m = m0 + wr * 64 + i * 16 + g * 4 + r;
#pragma unroll
                for (int j = 0; j < 4; ++j) {
                    int n = n0 + wc * 64 + j * 16 + c;
                    Cf[(size_t)m * N + n] = acc[i][j][r] + bias[n];
                }
            }
    } else {
        const int part = n0 >> 10;             // tile never crosses 1024-boundary
#pragma unroll
        for (int i = 0; i < 4; ++i)
#pragma unroll
            for (int r = 0; r < 4; ++r) {
                int m = m0 + wr * 64 + i * 16 + g * 4 + r;
                int b = m >> 11, tt = m & 2047;
#pragma unroll
                for (int j = 0; j < 4; ++j) {
                    int n = n0 + wc * 64 + j * 16 + c;
                    int e = n & 1023, hh = e >> 6, d = e & 63;
                    float v = acc[i][j][r] + bias[n];
                    u16 bv = f2bf(v);
                    if (part == 0)
                        Qb[(((size_t)b * 16 + hh) * 2048 + tt) * 64 + d] = bv;
                    else if (part == 1)
                        Kb[(((size_t)b * 16 + hh) * 2048 + tt) * 64 + d] = bv;
                    else
                        VbT[(((size_t)b * 16 + hh) * 64 + d) * 2048 + tt] = bv;
                }
            }
    }
}

// ---------------------------------------------------------------------------
// Flash attention, swapped-operand form; Q roped in-register at start.
// 1024 blocks, 256 threads (4 waves x 32 q each; block = 128 q rows).
__global__ __launch_bounds__(256, 3) void attn_fwd(
    const u16* __restrict__ Qb, const u16* __restrict__ Kb,
    const u16* __restrict__ VbT, u16* __restrict__ Ob,
    const float2* __restrict__ tab) {
    __shared__ __align__(16) u16 Kt[2][4096];   // [buf][kv=64][d=64] swizzled
    __shared__ __align__(16) u16 Vt[2][4096];   // [buf][d=64][kv=64] swizzled
    __shared__ __align__(16) u16 Pt[4][2048];   // per-wave [q=32][kv=64] swizzled
    const int tid = threadIdx.x, wv = tid >> 6, lane = tid & 63;
    const int g = lane >> 4, c = lane & 15;
    const int bid = blockIdx.x;                 // 0..1023
    const int xcd = bid & 7, slot = bid >> 3;
    const int bh = (xcd << 3) | (slot >> 4);
    const int blk = 15 - (slot & 15);
    const int b = bh >> 4, h = bh & 15;
    const int q0 = blk * 128;
    const int q0w = q0 + wv * 32;
    const int qlo = q0w + c, qhi = q0w + 16 + c;
    const float CSC = 0.18033688011112042f;     // 0.125 * log2(e)

    const u16* qp = Qb + ((size_t)bh * 2048 + qlo) * 64 + g * 8;
    const float2* tql = tab + qlo * 32 + g * 4;
    const float2* tqh = tab + qhi * 32 + g * 4;
    bf16x8 bq0l = ropeQK(*(const bf16x8*)(qp), tql);
    bf16x8 bq1l = ropeQK(*(const bf16x8*)(qp + 32), tql + 16);
    bf16x8 bq0h = ropeQK(*(const bf16x8*)(qp + 16 * 64), tqh);
    bf16x8 bq1h = ropeQK(*(const bf16x8*)(qp + 16 * 64 + 32), tqh + 16);

    float m_lo = -INFINITY, l_lo = 0.f;
    float m_hi = -INFINITY, l_hi = 0.f;
    f32x4 accL[4] = {}, accH[4] = {};

    const int stRow = tid >> 3;                 // 0..31
    const int stCol = (tid & 7) * 8;            // 0..56
    const u16* gK = Kb + (size_t)bh * 2048 * 64 + (size_t)stRow * 64 + stCol;
    const u16* gV = VbT + (size_t)bh * 64 * 2048 + (size_t)stRow * 2048 + stCol;
    const unsigned sw8 = (unsigned)(stRow & 7) << 4;
    const unsigned sAd0 = ((unsigned)(stRow * 128 + stCol * 2)) ^ sw8;
    const unsigned sAd1 = ((unsigned)((stRow + 32) * 128 + stCol * 2)) ^ sw8;
    const unsigned swz = (unsigned)(c & 7) << 4;
    char* pw = (char*)&Pt[wv][0];

    const int ktend = 2 * blk + 1;
    const int ktmax_w = (q0w + 31) >> 6;

    u16x8 kr0 = *(const u16x8*)(gK);
    u16x8 kr1 = *(const u16x8*)(gK + 32 * 64);
    u16x8 vr0 = *(const u16x8*)(gV);
    u16x8 vr1 = *(const u16x8*)(gV + 32 * 2048);
    *(u16x8*)((char*)Kt[0] + sAd0) = kr0;
    *(u16x8*)((char*)Kt[0] + sAd1) = kr1;
    *(u16x8*)((char*)Vt[0] + sAd0) = vr0;
    *(u16x8*)((char*)Vt[0] + sAd1) = vr1;
    int cur = 0;

    for (int kt = 0; kt <= ktend; ++kt) {
        __syncthreads();
        if (kt < ktend) {
            const u16* nK = gK + (size_t)(kt + 1) * 64 * 64;
            const u16* nV = gV + (size_t)(kt + 1) * 64;
            kr0 = *(const u16x8*)(nK);
            kr1 = *(const u16x8*)(nK + 32 * 64);
            vr0 = *(const u16x8*)(nV);
            vr1 = *(const u16x8*)(nV + 32 * 2048);
        }
        if (kt <= ktmax_w) {
            const char* Kc = (const char*)Kt[cur];
            const char* Vc = (const char*)Vt[cur];

            f32x4 sl[4] = {}, sh[4] = {};
#pragma unroll
            for (int j = 0; j < 4; ++j) {
                unsigned rb = (unsigned)((16 * j + c) * 128 + g * 16);
                bf16x8 ka0 = *(const bf16x8*)(Kc + (rb ^ swz));
                bf16x8 ka1 = *(const bf16x8*)(Kc + ((rb + 64) ^ swz));
                sl[j] = __builtin_amdgcn_mfma_f32_16x16x32_bf16(ka0, bq0l, sl[j], 0, 0, 0);
                sl[j] = __builtin_amdgcn_mfma_f32_16x16x32_bf16(ka1, bq1l, sl[j], 0, 0, 0);
                sh[j] = __builtin_amdgcn_mfma_f32_16x16x32_bf16(ka0, bq0h, sh[j], 0, 0, 0);
                sh[j] = __builtin_amdgcn_mfma_f32_16x16x32_bf16(ka1, bq1h, sh[j], 0, 0, 0);
            }

            const int kvb = kt * 64 + 4 * g;
            if (kt * 64 + 63 > q0w) {
#pragma unroll
                for (int j = 0; j < 4; ++j)
#pragma unroll
                    for (int r = 0; r < 4; ++r)
                        if (kvb + 16 * j + r > qlo) sl[j][r] = -INFINITY;
            }
            if (kt * 64 + 63 > q0w + 16) {
#pragma unroll
                for (int j = 0; j < 4; ++j)
#pragma unroll
                    for (int r = 0; r < 4; ++r)
                        if (kvb + 16 * j + r > qhi) sh[j][r] = -INFINITY;
            }

#pragma unroll
            for (int half = 0; half < 2; ++half) {
                f32x4* s = half ? sh : sl;
                float& m_r = half ? m_hi : m_lo;
                float& l_r = half ? l_hi : l_lo;
                f32x4* acc = half ? accH : accL;
                float mx = -INFINITY;
#pragma unroll
                for (int j = 0; j < 4; ++j)
#pragma unroll
                    for (int r = 0; r < 4; ++r) mx = fmaxf(mx, s[j][r]);
                mx = fmaxf(mx, __shfl_xor(mx, 16));
                mx = fmaxf(mx, __shfl_xor(mx, 32));
                if (!__all((mx - m_r) * CSC <= 8.f)) {
                    float mn = fmaxf(m_r, mx);
                    float al = exp2v((m_r - mn) * CSC);
                    l_r *= al;
#pragma unroll
                    for (int dj = 0; dj < 4; ++dj) acc[dj] *= al;
                    m_r = mn;
                }
                const float mc = m_r * CSC;
                float sum = 0.f;
                u32 pp[8];
#pragma unroll
                for (int j = 0; j < 4; ++j) {
#pragma unroll
                    for (int t2 = 0; t2 < 2; ++t2) {
                        float p0 = exp2v(fmaf(s[j][2 * t2], CSC, -mc));
                        float p1 = exp2v(fmaf(s[j][2 * t2 + 1], CSC, -mc));
                        sum += p0 + p1;
                        pp[j * 2 + t2] = cvtpk(p0, p1);
                    }
                }
                sum += __shfl_xor(sum, 16);
                sum += __shfl_xor(sum, 32);
                l_r += sum;
                unsigned rq = (unsigned)(c + 16 * half) * 128;
#pragma unroll
                for (int j = 0; j < 4; ++j) {
                    uint2 w2;
                    w2.x = pp[j * 2];
                    w2.y = pp[j * 2 + 1];
                    *(uint2*)(pw + ((rq + j * 32 + g * 8) ^ swz)) = w2;
                }
            }

#pragma unroll
            for (int ks = 0; ks < 2; ++ks) {
                bf16x8 pbl = *(const bf16x8*)(pw + ((unsigned)(c * 128 + ks * 64 + g * 16) ^ swz));
                bf16x8 pbh = *(const bf16x8*)(pw + ((unsigned)((c + 16) * 128 + ks * 64 + g * 16) ^ swz));
#pragma unroll
                for (int dj = 0; dj < 4; ++dj) {
                    unsigned vb = (unsigned)((dj * 16 + c) * 128 + ks * 64 + g * 16) ^ swz;
                    bf16x8 va = *(const bf16x8*)(Vc + vb);
                    accL[dj] = __builtin_amdgcn_mfma_f32_16x16x32_bf16(va, pbl, accL[dj], 0, 0, 0);
                    accH[dj] = __builtin_amdgcn_mfma_f32_16x16x32_bf16(va, pbh, accH[dj], 0, 0, 0);
                }
            }
        }

        if (kt < ktend) {
            int nb = cur ^ 1;
            *(u16x8*)((char*)Kt[nb] + sAd0) = kr0;
            *(u16x8*)((char*)Kt[nb] + sAd1) = kr1;
            *(u16x8*)((char*)Vt[nb] + sAd0) = vr0;
            *(u16x8*)((char*)Vt[nb] + sAd1) = vr1;
            cur = nb;
        }
    }

#pragma unroll
    for (int half = 0; half < 2; ++half) {
        const f32x4* acc = half ? accH : accL;
        float inv = 1.f / (half ? l_hi : l_lo);
        int q = half ? qhi : qlo;
        u16* ob = Ob + ((size_t)b * 2048 + q) * 1024 + h * 64;
#pragma unroll
        for (int dj = 0; dj < 4; ++dj) {
            f32x4 o = acc[dj] * inv;
            uint2 w;
            w.x = cvtpk(o[0], o[1]);
            w.y = cvtpk(o[2], o[3]);
            *(uint2*)(ob + dj * 16 + 4 * g) = w;
        }
    }
}

// ---------------------------------------------------------------------------
extern "C" void kernel_launch(void* const* d_in, const int* in_sizes, int n_in,
                              void* d_out, int out_size, void* d_ws, size_t ws_size,
                              hipStream_t stream) {
    const float* x = (const float*)d_in[0];
    const float* Wqkv = (const float*)d_in[1];
    const float* bqkv = (const float*)d_in[2];
    const float* Wproj = (const float*)d_in[3];
    const float* bproj = (const float*)d_in[4];
    float* out = (float*)d_out;

    char* ws = (char*)d_ws;
    u16* xb = (u16*)(ws);                       // 16,777,216 B; reused as Ob
    u16* WqkvT = (u16*)(ws + 16777216);         //  6,291,456 B
    u16* WprojT = (u16*)(ws + 23068672);        //  2,097,152 B
    u16* Qb = (u16*)(ws + 25165824);            // 16,777,216 B
    u16* Kb = (u16*)(ws + 41943040);            // 16,777,216 B
    u16* VbT = (u16*)(ws + 58720256);           // 16,777,216 B
    float2* tab = (float2*)(ws + 75497472);     //    524,288 B  (total ~76 MB)

    f2bker<<<4096, 256, 0, stream>>>(x, xb);
    wtrans<<<dim3(48, 16), 256, 0, stream>>>(Wqkv, WqkvT, 1024, 3072);
    wtrans<<<dim3(16, 16), 256, 0, stream>>>(Wproj, WprojT, 1024, 1024);
    rope_tab<<<256, 256, 0, stream>>>(tab);
    gemm2p<1><<<1536, 256, 0, stream>>>(xb, WqkvT, bqkv, nullptr, Qb, Kb, VbT,
                                        3072, 24);
    rope_ip<<<16384, 256, 0, stream>>>(Kb, tab);
    attn_fwd<<<1024, 256, 0, stream>>>(Qb, Kb, VbT, xb /*Ob*/, tab);
    gemm2p<0><<<512, 256, 0, stream>>>(xb, WprojT, bproj, out,
                                       nullptr, nullptr, nullptr, 1024, 8);
}